// Round 6
// baseline (17004.143 us; speedup 1.0000x reference)
//
#include <hip/hip_runtime.h>
#include <hip/hip_cooperative_groups.h>
#include <math.h>

#define LSEQ 256
#define NB   512   // batch
#define ISZ  512   // input size
#define HSZ  1024  // hidden size

typedef __attribute__((ext_vector_type(8))) short bfrag;   // 8 bf16 (bit pattern in shorts)
typedef __attribute__((ext_vector_type(4))) float f32x4;

__device__ __forceinline__ f32x4 mfma_bf16(bfrag a, bfrag b, f32x4 c) {
    return __builtin_amdgcn_mfma_f32_16x16x32_bf16(a, b, c, 0, 0, 0);
}

// fp32 -> bf16 hi + bf16 lo (both RNE).  hi+lo reconstructs ~17 mantissa bits.
__device__ __forceinline__ void split_bf16(float v, short& hi, short& lo) {
    __bf16 h = (__bf16)v;
    float  r = v - (float)h;
    __bf16 l = (__bf16)r;
    hi = __builtin_bit_cast(short, h);
    lo = __builtin_bit_cast(short, l);
}

// tanh(x) = 1 - 2/(e^{2x}+1)  (exact identity; correct limits at +-inf, no NaN)
__device__ __forceinline__ float fast_tanh(float x) {
    float e = __expf(2.0f * x);
    return 1.0f - 2.0f / (e + 1.0f);
}

// Pre-split an fp32 array into hi/lo bf16 planes. n4 = n/4.
__global__ __launch_bounds__(256) void split_kernel(const float* __restrict__ in,
                                                    short* __restrict__ hi,
                                                    short* __restrict__ lo, int n4) {
    int i = blockIdx.x * 256 + threadIdx.x;
    if (i >= n4) return;
    float4 v = ((const float4*)in)[i];
    short h0, l0, h1, l1, h2, l2, h3, l3;
    split_bf16(v.x, h0, l0); split_bf16(v.y, h1, l1);
    split_bf16(v.z, h2, l2); split_bf16(v.w, h3, l3);
    ((short4*)hi)[i] = make_short4(h0, h1, h2, h3);
    ((short4*)lo)[i] = make_short4(l0, l1, l2, l3);
}

// ---------------------------------------------------------------------------
// Generic tiled MFMA GEMM (phases 1, 3, and fallbacks). UNCHANGED since R2.
// C[M,N] = act( A1@B1^T (+ A2@B2^T) (+ Cadd) (+ bias1 + bias2) )
// A fp32 row-major [M,K] (split to bf16 hi/lo on the fly during LDS staging).
// B pre-split bf16 hi/lo, row-major [N,K] (torch weight layout).
// MFMA 16x16x32 bf16, 3-product hi/lo scheme (~fp32 accuracy; lo*lo dropped).
// A and B fragments use the SAME (lane,j)->k mapping, so any within-K-32
// permutation error in the assumed operand layout cancels algebraically.
// LDS chunk layout [kslot][row] of 16B chunks -> conflict-free ds_read_b128.
// ACT: 0 none, 1 tanh, 2 relu.
// SWZ: 1 = XCD-chunked row-major 1D grid, 2 = XCD-chunked col-major 1D grid.
// ---------------------------------------------------------------------------
template <int BM, int BN, int WR, int WC, int ACT, int SWZ, int NSB>
__global__ __launch_bounds__(256) void mfma_gemm(
    const float* __restrict__ A1, int lda1,
    const short* __restrict__ B1hi, const short* __restrict__ B1lo, int K1,
    const float* __restrict__ A2, int lda2,
    const short* __restrict__ B2hi, const short* __restrict__ B2lo, int K2,
    const float* __restrict__ Cadd, int ldadd,
    const float* __restrict__ bias1, const float* __restrict__ bias2,
    float* __restrict__ C, int ldc)
{
    constexpr int WM = BM / WR, WN = BN / WC;
    constexpr int FM = WM / 16, FN = WN / 16;
    constexpr int NACH = 4 * BM;   // A chunks (8 bf16 each) per K-tile
    constexpr int NBCH = 4 * BN;
    constexpr int NA_IT = (NACH + 255) / 256;
    constexpr int NB_IT = (NBCH + 255) / 256;
    static_assert(WR * WC == 4, "4 waves");
    static_assert(NACH % 256 == 0 || NACH < 256, "A staging geometry");
    static_assert(NBCH % 256 == 0 || NBCH < 256, "B staging geometry");

    __shared__ short sAhi[NACH * 8], sAlo[NACH * 8];
    __shared__ short sBhi[NBCH * 8], sBlo[NBCH * 8];

    const int tid  = threadIdx.x;
    const int lane = tid & 63;
    const int w    = tid >> 6;
    const int wr   = w / WC, wc = w % WC;
    const int r16  = lane & 15;   // A row / B col fragment index; out col
    const int ks   = lane >> 4;   // k-slot 0..3 (8 bf16 each); out 4-row group

    int id = blockIdx.x;
    {
        const int tot = gridDim.x;
        id = (id & 7) * (tot >> 3) + (id >> 3);   // XCD-chunked (grid % 8 == 0)
    }
    int row0, col0;
    if (SWZ == 1) { row0 = (id / NSB) * BM; col0 = (id % NSB) * BN; }
    else          { col0 = (id / NSB) * BN; row0 = (id % NSB) * BM; }

    f32x4 acc[FM][FN] = {};

    for (int seg = 0; seg < 2; ++seg) {
        const float* A = seg ? A2 : A1;
        if (A == nullptr) continue;
        const int    lda = seg ? lda2 : lda1;
        const int    K   = seg ? K2 : K1;
        const short* Bh  = seg ? B2hi : B1hi;
        const short* Bl  = seg ? B2lo : B1lo;

        const float* ApA[NA_IT];
        const short* BhP[NB_IT];
        const short* BlP[NB_IT];
        int posA[NA_IT], posB[NB_IT];
        #pragma unroll
        for (int i = 0; i < NA_IT; ++i) {
            const int c = tid + 256 * i;
            const int sa = c & 3, ra = c >> 2;
            posA[i] = (sa * BM + ra) * 8;
            ApA[i]  = A + (size_t)(row0 + ra) * lda + sa * 8;
        }
        #pragma unroll
        for (int i = 0; i < NB_IT; ++i) {
            const int c = tid + 256 * i;
            const int sb = c & 3, cb = c >> 2;
            posB[i] = (sb * BN + cb) * 8;
            BhP[i]  = Bh + (size_t)(col0 + cb) * K + sb * 8;
            BlP[i]  = Bl + (size_t)(col0 + cb) * K + sb * 8;
        }
        const bool aOk = (NACH >= 256) || (tid < NACH);

        float4 av0[NA_IT], av1[NA_IT];
        bfrag  bhv[NB_IT], blv[NB_IT];
        #pragma unroll
        for (int i = 0; i < NA_IT; ++i)
            if (aOk) { av0[i] = *(const float4*)(ApA[i]); av1[i] = *(const float4*)(ApA[i] + 4); }
        #pragma unroll
        for (int i = 0; i < NB_IT; ++i) {
            bhv[i] = *(const bfrag*)(BhP[i]);
            blv[i] = *(const bfrag*)(BlP[i]);
        }

        for (int k0 = 0; k0 < K; k0 += 32) {
            __syncthreads();
            #pragma unroll
            for (int i = 0; i < NA_IT; ++i) {
                if (aOk) {
                    float af[8] = {av0[i].x, av0[i].y, av0[i].z, av0[i].w,
                                   av1[i].x, av1[i].y, av1[i].z, av1[i].w};
                    bfrag hv, lv;
                    #pragma unroll
                    for (int j = 0; j < 8; ++j) {
                        short h, l;
                        split_bf16(af[j], h, l);
                        hv[j] = h; lv[j] = l;
                    }
                    *(bfrag*)&sAhi[posA[i]] = hv;
                    *(bfrag*)&sAlo[posA[i]] = lv;
                }
            }
            #pragma unroll
            for (int i = 0; i < NB_IT; ++i) {
                *(bfrag*)&sBhi[posB[i]] = bhv[i];
                *(bfrag*)&sBlo[posB[i]] = blv[i];
            }
            __syncthreads();

            if (k0 + 32 < K) {
                #pragma unroll
                for (int i = 0; i < NA_IT; ++i)
                    if (aOk) {
                        av0[i] = *(const float4*)(ApA[i] + k0 + 32);
                        av1[i] = *(const float4*)(ApA[i] + k0 + 36);
                    }
                #pragma unroll
                for (int i = 0; i < NB_IT; ++i) {
                    bhv[i] = *(const bfrag*)(BhP[i] + k0 + 32);
                    blv[i] = *(const bfrag*)(BlP[i] + k0 + 32);
                }
            }

            bfrag ah[FM], al[FM], bhf[FN], blf[FN];
            #pragma unroll
            for (int fi = 0; fi < FM; ++fi) {
                const int idx = (ks * BM + wr * WM + fi * 16 + r16) * 8;
                ah[fi] = *(const bfrag*)&sAhi[idx];
                al[fi] = *(const bfrag*)&sAlo[idx];
            }
            #pragma unroll
            for (int fj = 0; fj < FN; ++fj) {
                const int idx = (ks * BN + wc * WN + fj * 16 + r16) * 8;
                bhf[fj] = *(const bfrag*)&sBhi[idx];
                blf[fj] = *(const bfrag*)&sBlo[idx];
            }
            #pragma unroll
            for (int fi = 0; fi < FM; ++fi)
                #pragma unroll
                for (int fj = 0; fj < FN; ++fj)
                    acc[fi][fj] = mfma_bf16(ah[fi], bhf[fj], acc[fi][fj]);  // hi*hi
            #pragma unroll
            for (int fi = 0; fi < FM; ++fi)
                #pragma unroll
                for (int fj = 0; fj < FN; ++fj)
                    acc[fi][fj] = mfma_bf16(ah[fi], blf[fj], acc[fi][fj]);  // hi*lo
            #pragma unroll
            for (int fi = 0; fi < FM; ++fi)
                #pragma unroll
                for (int fj = 0; fj < FN; ++fj)
                    acc[fi][fj] = mfma_bf16(al[fi], bhf[fj], acc[fi][fj]);  // lo*hi
        }
    }

    // epilogue: C/D layout col = lane&15, row = (lane>>4)*4 + reg  [m89-verified]
    const int baseRow = row0 + wr * WM;
    const int baseCol = col0 + wc * WN;
    #pragma unroll
    for (int fi = 0; fi < FM; ++fi)
        #pragma unroll
        for (int fj = 0; fj < FN; ++fj)
            #pragma unroll
            for (int r = 0; r < 4; ++r) {
                const int row = baseRow + fi * 16 + ks * 4 + r;
                const int col = baseCol + fj * 16 + r16;
                float v = acc[fi][fj][r];
                if (Cadd)  v += Cadd[(size_t)row * ldadd + col];
                if (bias1) v += bias1[col];
                if (bias2) v += bias2[col];
                if (ACT == 1) v = fast_tanh(v);
                if (ACT == 2) v = fmaxf(v, 0.f);
                C[(size_t)row * ldc + col] = v;
            }
}

// ---------------------------------------------------------------------------
// Persistent cooperative phase-2 scan, W_hh-RESIDENT version.
// Grid = 256 blocks x 256 threads (1 block/CU). Per block: 64 batch rows x
// 32 hidden cols. The block's W_hh col-panel (32 cols x 1024 k x hi/lo =
// 128 KB) is staged into LDS ONCE and reused by all 256 steps -> B staging
// and its global traffic vanish from the k-loop. h is carried between steps
// as pre-split bf16 hi/lo planes (epilogue splits; last step writes fp32).
// k-loop per thread per k-tile: 2 ds_write + 6 ds_read + 6 MFMA, 1 barrier
// (single-barrier double-buffered A staging, fully unrolled -> static idx).
// Per-product accumulators give same-acc MFMA spacing 6 (1 wave/SIMD -> ILP
// is the only latency hiding). Fragment/LDS maps identical to mfma_gemm.
// XCD map: row-panel == blockIdx&7 == XCD -> h panel + xw slice XCD-local.
// Correctness relies only on __threadfence + grid.sync [G16].
// LDS: 128 KB (B) + 16 KB (A dbuf) = 144 KB <= 160 KB -> 1 block/CU.
// ---------------------------------------------------------------------------
__global__ __launch_bounds__(256) void rnn_scan_coop(
    short* __restrict__ s0hi, short* __restrict__ s0lo,   // h plane set 0 (holds split h0 at entry)
    short* __restrict__ s1hi, short* __restrict__ s1lo,   // h plane set 1
    const short* __restrict__ Whi, const short* __restrict__ Wlo,
    const float* __restrict__ xw,
    float* __restrict__ h_out)
{
    __shared__ short sBhi[32768], sBlo[32768];       // 64 KB + 64 KB resident W panel
    __shared__ short sAhi[2][2048], sAlo[2][2048];   // 2 x (4 KB + 4 KB) A dbuf

    const int tid  = threadIdx.x;
    const int lane = tid & 63;
    const int w    = tid >> 6;
    const int wr   = w >> 1, wc = w & 1;   // 2x2 waves: WM=32 (FM=2), WN=16 (FN=1)
    const int r16  = lane & 15;
    const int ks   = lane >> 4;

    int id = blockIdx.x;
    id = (id & 7) * 32 + (id >> 3);        // row-panel == bid&7 == XCD (perf only)
    const int row0 = (id >> 5) * 64;       // 8 row panels
    const int col0 = (id & 31) * 32;       // 32 col panels

    // Stage resident W_hh panel: 4096 chunks (8 bf16 = 16B) per plane.
    // chunk c -> (col = c&31, kchunk = c>>5); LDS offset = c*16B.
    // Read side: chunk(kt,ks,col j) = (kt*4+ks)*32 + j  -> consistent.
    for (int c = tid; c < 4096; c += 256) {
        const int col = c & 31, kc = c >> 5;
        *(bfrag*)&sBhi[c * 8] = *(const bfrag*)(Whi + (size_t)(col0 + col) * HSZ + kc * 8);
        *(bfrag*)&sBlo[c * 8] = *(const bfrag*)(Wlo + (size_t)(col0 + col) * HSZ + kc * 8);
    }

    // A staging role: 256 chunks per k-tile, exactly 1 per thread.
    const int sa = tid & 3, ra = tid >> 2;            // slot, row
    const int posA = (sa * 64 + ra) * 8;              // [slot][row] 16B chunks

    cooperative_groups::grid_group grid = cooperative_groups::this_grid();
    __syncthreads();   // W panel resident

    for (int t = 0; t < LSEQ; ++t) {
        const short* rHi = (t & 1) ? s1hi : s0hi;
        const short* rLo = (t & 1) ? s1lo : s0lo;
        short* wHi = (t & 1) ? s0hi : s1hi;
        short* wLo = (t & 1) ? s0lo : s1lo;

        // xw prefetch: 8 scalars consumed in the epilogue; the ~6000-cycle
        // k-loop hides the HBM latency (xw streams from HBM, 2 MB/step).
        float xwv[8];
        {
            const size_t xb = (size_t)t * NB * HSZ;
            #pragma unroll
            for (int fi = 0; fi < 2; ++fi)
                #pragma unroll
                for (int rr = 0; rr < 4; ++rr)
                    xwv[fi * 4 + rr] =
                        xw[xb + (size_t)(row0 + wr * 32 + fi * 16 + ks * 4 + rr) * HSZ
                           + (col0 + wc * 16 + r16)];
        }

        const short* aHi = rHi + (size_t)(row0 + ra) * HSZ + sa * 8;
        const short* aLo = rLo + (size_t)(row0 + ra) * HSZ + sa * 8;

        bfrag rh[2], rl[2];                 // 2-deep reg prefetch (static idx via unroll)
        rh[0] = *(const bfrag*)(aHi);
        rl[0] = *(const bfrag*)(aLo);

        f32x4 ahh[2] = {}, ahl[2] = {}, alh[2] = {};   // per-product accumulators

        #pragma unroll
        for (int kt = 0; kt < 32; ++kt) {
            const int cb = kt & 1;
            // store tile kt (loaded last iter); safe: readers of sA[cb]
            // finished before the barrier of iteration kt-1.
            *(bfrag*)&sAhi[cb][posA] = rh[cb];
            *(bfrag*)&sAlo[cb][posA] = rl[cb];
            if (kt + 1 < 32) {              // prefetch tile kt+1
                rh[cb ^ 1] = *(const bfrag*)(aHi + (kt + 1) * 32);
                rl[cb ^ 1] = *(const bfrag*)(aLo + (kt + 1) * 32);
            }
            __syncthreads();                // sA[cb] visible to all waves

            bfrag ah0 = *(const bfrag*)&sAhi[cb][(ks * 64 + wr * 32 + r16) * 8];
            bfrag ah1 = *(const bfrag*)&sAhi[cb][(ks * 64 + wr * 32 + 16 + r16) * 8];
            bfrag al0 = *(const bfrag*)&sAlo[cb][(ks * 64 + wr * 32 + r16) * 8];
            bfrag al1 = *(const bfrag*)&sAlo[cb][(ks * 64 + wr * 32 + 16 + r16) * 8];
            bfrag bh  = *(const bfrag*)&sBhi[((kt * 4 + ks) * 32 + wc * 16 + r16) * 8];
            bfrag bl  = *(const bfrag*)&sBlo[((kt * 4 + ks) * 32 + wc * 16 + r16) * 8];

            ahh[0] = mfma_bf16(ah0, bh, ahh[0]);   // same-acc spacing = 6 MFMAs
            ahh[1] = mfma_bf16(ah1, bh, ahh[1]);
            ahl[0] = mfma_bf16(ah0, bl, ahl[0]);
            ahl[1] = mfma_bf16(ah1, bl, ahl[1]);
            alh[0] = mfma_bf16(al0, bh, alh[0]);
            alh[1] = mfma_bf16(al1, bh, alh[1]);
        }

        // epilogue: h' = tanh(xw_t + acc); C/D map col=lane&15,
        // row=(lane>>4)*4+reg [m89-verified]. Steps 0..254 store split
        // bf16 planes (identical rounding to on-the-fly split); last
        // step stores fp32 into d_out's h region.
        #pragma unroll
        for (int fi = 0; fi < 2; ++fi)
            #pragma unroll
            for (int rr = 0; rr < 4; ++rr) {
                float v = ahh[fi][rr] + ahl[fi][rr] + alh[fi][rr] + xwv[fi * 4 + rr];
                v = fast_tanh(v);
                const int row = row0 + wr * 32 + fi * 16 + ks * 4 + rr;
                const int col = col0 + wc * 16 + r16;
                if (t == LSEQ - 1) {
                    h_out[(size_t)row * HSZ + col] = v;
                } else {
                    short hh, ll;
                    split_bf16(v, hh, ll);
                    wHi[(size_t)row * HSZ + col] = hh;
                    wLo[(size_t)row * HSZ + col] = ll;
                }
            }

        __threadfence();   // device-scope release of h stores (cross-XCD)
        grid.sync();
    }
}

extern "C" void kernel_launch(void* const* d_in, const int* in_sizes, int n_in,
                              void* d_out, int out_size, void* d_ws, size_t ws_size,
                              hipStream_t stream)
{
    const float* x    = (const float*)d_in[0];  // [L, N, I]
    const float* h0   = (const float*)d_in[1];  // [N, H]
    const float* W_ih = (const float*)d_in[2];  // [H, I]
    const float* W_hh = (const float*)d_in[3];  // [H, H]
    const float* b_ih = (const float*)d_in[4];  // [H]
    const float* b_hh = (const float*)d_in[5];  // [H]
    const float* W_fc = (const float*)d_in[6];  // [I, H]
    const float* b_fc = (const float*)d_in[7];  // [I]

    float* out   = (float*)d_out;
    float* y_out = out;                     // [N, I]
    float* h_out = out + (size_t)NB * ISZ;  // [N, H] final hidden

    char*  ws  = (char*)d_ws;
    size_t off = 0;
    auto take = [&](size_t bytes) {
        char* p = ws + off;
        off += (bytes + 255) & ~(size_t)255;
        return p;
    };
    short* whh_hi = (short*)take((size_t)HSZ * HSZ * 2);
    short* whh_lo = (short*)take((size_t)HSZ * HSZ * 2);
    short* wih_hi = (short*)take((size_t)HSZ * ISZ * 2);
    short* wih_lo = (short*)take((size_t)HSZ * ISZ * 2);
    short* wfc_hi = (short*)take((size_t)ISZ * HSZ * 2);
    short* wfc_lo = (short*)take((size_t)ISZ * HSZ * 2);
    float* hbufA  = (float*)take((size_t)NB * HSZ * 4);   // fp32 (fallback paths)
    float* hbufB  = (float*)take((size_t)NB * HSZ * 4);
    short* h0s_hi = (short*)take((size_t)NB * HSZ * 2);   // split h carry, set 0
    short* h0s_lo = (short*)take((size_t)NB * HSZ * 2);
    short* h1s_hi = (short*)take((size_t)NB * HSZ * 2);   // split h carry, set 1
    short* h1s_lo = (short*)take((size_t)NB * HSZ * 2);
    float* xw     = (float*)take((size_t)LSEQ * NB * HSZ * 4);  // 537 MB
    const bool pathA = (ws_size >= off);   // constant per run -> graph-safe

    split_kernel<<<dim3(HSZ * HSZ / 4 / 256), 256, 0, stream>>>(W_hh, whh_hi, whh_lo, HSZ * HSZ / 4);
    split_kernel<<<dim3(HSZ * ISZ / 4 / 256), 256, 0, stream>>>(W_ih, wih_hi, wih_lo, HSZ * ISZ / 4);
    split_kernel<<<dim3(ISZ * HSZ / 4 / 256), 256, 0, stream>>>(W_fc, wfc_hi, wfc_lo, ISZ * HSZ / 4);

    if (pathA) {
        // Phase 1: xw = x @ W_ih^T + b_ih + b_hh   [L*N, H], 128x128 tiles
        // (m93 lever: 48 MFMA / 16 ds_read_b128 per K-tile -> MFMA-issue-bound)
        mfma_gemm<128, 128, 2, 2, 0, 1, HSZ / 128>
            <<<dim3((LSEQ * NB / 128) * (HSZ / 128)), 256, 0, stream>>>(
                x, ISZ, wih_hi, wih_lo, ISZ,
                nullptr, 0, nullptr, nullptr, 0,
                nullptr, 0, b_ih, b_hh, xw, HSZ);

        // h0 -> split planes (set 0) for the coop scan
        split_kernel<<<dim3(NB * HSZ / 4 / 256), 256, 0, stream>>>(h0, h0s_hi, h0s_lo, NB * HSZ / 4);

        // Phase 2 (primary): persistent cooperative W-resident scan.
        short* a0 = h0s_hi; short* a1 = h0s_lo; short* a2 = h1s_hi; short* a3 = h1s_lo;
        const short* a4 = whh_hi; const short* a5 = whh_lo;
        const float* a6 = xw; float* a7 = h_out;
        void* args[] = {(void*)&a0, (void*)&a1, (void*)&a2, (void*)&a3,
                        (void*)&a4, (void*)&a5, (void*)&a6, (void*)&a7};
        hipError_t e = hipLaunchCooperativeKernel((const void*)rnn_scan_coop,
                                                  dim3(256), dim3(256), args, 0, stream);
        if (e != hipSuccess) {
            // Fallback: per-step launches (same math, fp32 h carry)
            const float* hprev = h0;
            for (int t = 0; t < LSEQ; ++t) {
                float* hnext = (t == LSEQ - 1) ? h_out : ((t & 1) ? hbufB : hbufA);
                mfma_gemm<32, 64, 2, 2, 1, 2, NB / 32>
                    <<<dim3((NB / 32) * (HSZ / 64)), 256, 0, stream>>>(
                        hprev, HSZ, whh_hi, whh_lo, HSZ,
                        nullptr, 0, nullptr, nullptr, 0,
                        xw + (size_t)t * NB * HSZ, HSZ, nullptr, nullptr, hnext, HSZ);
                hprev = hnext;
            }
        }
    } else {
        // Lean fallback (small ws): fused per-step x_t@W_ih^T + h@W_hh^T
        const float* hprev = h0;
        for (int t = 0; t < LSEQ; ++t) {
            float* hnext = (t == LSEQ - 1) ? h_out : ((t & 1) ? hbufB : hbufA);
            mfma_gemm<32, 64, 2, 2, 1, 2, NB / 32>
                <<<dim3((NB / 32) * (HSZ / 64)), 256, 0, stream>>>(
                    hprev, HSZ, whh_hi, whh_lo, HSZ,
                    x + (size_t)t * NB * ISZ, ISZ, wih_hi, wih_lo, ISZ,
                    nullptr, 0, b_ih, b_hh, hnext, HSZ);
            hprev = hnext;
        }
    }

    // Phase 3: y = relu(h_final @ W_fc^T + b_fc)
    mfma_gemm<32, 64, 2, 2, 2, 2, NB / 32>
        <<<dim3((NB / 32) * (ISZ / 64)), 256, 0, stream>>>(
            h_out, HSZ, wfc_hi, wfc_lo, HSZ,
            nullptr, 0, nullptr, nullptr, 0,
            nullptr, 0, b_fc, nullptr, y_out, ISZ);
}